// Round 2
// baseline (468.893 us; speedup 1.0000x reference)
//
#include <hip/hip_runtime.h>
#include <math.h>

#define EPS 1e-5f
constexpr int D = 64;
constexpr int SCAN_ELEMS = 2048;   // elements per scan1 block (256 thr * 8)

// ---------------- K1: degree histogram ----------------
__global__ void hist_kernel(const int* __restrict__ ei, int* __restrict__ deg,
                            int E, int N) {
    int e = blockIdx.x * blockDim.x + threadIdx.x;
    if (e >= E) return;
    int dst = ei[E + e];
    dst = min(max(dst, 0), N - 1);
    atomicAdd(&deg[dst], 1);
}

// ---------------- K2a: per-block exclusive scan ----------------
__global__ void scan1_kernel(const int* __restrict__ deg,
                             int* __restrict__ row_local,
                             int* __restrict__ partials, int N) {
    __shared__ int lds[256];
    int t = threadIdx.x;
    int base = blockIdx.x * SCAN_ELEMS;
    int v[8];
    int s = 0;
#pragma unroll
    for (int i = 0; i < 8; ++i) {
        int idx = base + t * 8 + i;
        int d = (idx < N) ? deg[idx] : 0;
        v[i] = s;           // exclusive within thread
        s += d;
    }
    lds[t] = s;
    __syncthreads();
    for (int off = 1; off < 256; off <<= 1) {
        int val = (t >= off) ? lds[t - off] : 0;
        __syncthreads();
        lds[t] += val;
        __syncthreads();
    }
    int thread_off = (t > 0) ? lds[t - 1] : 0;
    if (t == 255) partials[blockIdx.x] = lds[255];
#pragma unroll
    for (int i = 0; i < 8; ++i) {
        int idx = base + t * 8 + i;
        if (idx < N) row_local[idx] = thread_off + v[i];
    }
}

// ---------------- K2b: scan the block partials (nb <= 64) ----------------
__global__ void scan2_kernel(int* partials, int nb) {
    int t = threadIdx.x;
    int orig = (t < nb) ? partials[t] : 0;
    int v = orig;
    for (int off = 1; off < 64; off <<= 1) {
        int u = __shfl_up(v, off, 64);
        if (t >= off) v += u;
    }
    if (t < nb) partials[t] = v - orig;   // exclusive
}

// ---------------- K2c: add block offsets -> row_ptr, cursor ----------------
__global__ void scan3_kernel(const int* __restrict__ row_local,
                             const int* __restrict__ partials,
                             int* __restrict__ row_ptr, int* __restrict__ cursor,
                             int N, int E) {
    int i = blockIdx.x * blockDim.x + threadIdx.x;
    if (i < N) {
        int r = row_local[i] + partials[i / SCAN_ELEMS];
        row_ptr[i] = r;
        cursor[i] = r;
    } else if (i == N) {
        row_ptr[N] = E;
    }
}

// ---------------- K3: bucket fill (CSR adjacency) ----------------
__global__ void fill_kernel(const int* __restrict__ ei, int* __restrict__ cursor,
                            int* __restrict__ adj, int E, int N) {
    int e = blockIdx.x * blockDim.x + threadIdx.x;
    if (e >= E) return;
    int src = ei[e];
    int dst = ei[E + e];
    src = min(max(src, 0), N - 1);
    dst = min(max(dst, 0), N - 1);
    int pos = atomicAdd(&cursor[dst], 1);
    adj[pos] = src;
}

// ------- K4: gather + mean + linear + global stats, one wave per node -------
__global__ __launch_bounds__(256) void fused_kernel(
        const float* __restrict__ x, const int* __restrict__ row_ptr,
        const int* __restrict__ adj, const float* __restrict__ Wl,
        const float* __restrict__ bl, const float* __restrict__ Wr,
        float* __restrict__ out, float* stats, int N) {
    const int lane = threadIdx.x & 63;
    const int wid = blockIdx.x * (blockDim.x >> 6) + (threadIdx.x >> 6);
    const int nwaves = gridDim.x * (blockDim.x >> 6);

    float wl[D], wr[D];
#pragma unroll
    for (int d4 = 0; d4 < D / 4; ++d4) {
        float4 a = *(const float4*)&Wl[lane * D + d4 * 4];
        float4 b = *(const float4*)&Wr[lane * D + d4 * 4];
        wl[d4 * 4 + 0] = a.x; wl[d4 * 4 + 1] = a.y;
        wl[d4 * 4 + 2] = a.z; wl[d4 * 4 + 3] = a.w;
        wr[d4 * 4 + 0] = b.x; wr[d4 * 4 + 1] = b.y;
        wr[d4 * 4 + 2] = b.z; wr[d4 * 4 + 3] = b.w;
    }
    const float bj = bl[lane];

    float ls = 0.0f, lsq = 0.0f;
    for (int n = wid; n < N; n += nwaves) {
        int r0 = row_ptr[n];
        int r1 = row_ptr[n + 1];
        int deg = r1 - r0;
        float s = 0.0f;
        for (int base = r0; base < r1; base += 64) {
            int m = min(64, r1 - base);
            int vidx = (base + lane < r1) ? adj[base + lane] : 0;
            for (int j = 0; j < m; ++j) {
                int src = (int)__builtin_amdgcn_readlane((unsigned)vidx, (unsigned)j);
                s += x[src * D + lane];
            }
        }
        float inv_c = 1.0f / fmaxf((float)deg, 1.0f);
        float sj = s * inv_c;               // mean neighbor feature, col=lane
        float xj = x[n * D + lane];
        float accl = 0.0f, accr = 0.0f;
#pragma unroll
        for (int d = 0; d < D; ++d) {
            float sd = __uint_as_float(
                __builtin_amdgcn_readlane(__float_as_uint(sj), d));
            float xd = __uint_as_float(
                __builtin_amdgcn_readlane(__float_as_uint(xj), d));
            accl = fmaf(sd, wl[d], accl);
            accr = fmaf(xd, wr[d], accr);
        }
        float v = accl + accr + bj;
        out[n * D + lane] = v;
        ls += v;
        lsq += v * v;
    }
    for (int off = 32; off > 0; off >>= 1) {
        ls += __shfl_down(ls, off, 64);
        lsq += __shfl_down(lsq, off, 64);
    }
    if (lane == 0) {
        atomicAdd(&stats[0], ls);
        atomicAdd(&stats[1], lsq);
    }
}

// ---------------- K5: in-place graph layernorm on d_out ----------------
__global__ void norm_kernel(const float* __restrict__ stats,
                            const float* __restrict__ lw,
                            const float* __restrict__ lb,
                            float* out, long long M4) {
    long long i = (long long)blockIdx.x * blockDim.x + threadIdx.x;
    if (i >= M4) return;
    const float inv_M = 1.0f / (float)(M4 * 4);
    float mu = stats[0] * inv_M;
    float var = stats[1] * inv_M - mu * mu;
    float rs = 1.0f / sqrtf(var + EPS);
    float4 v = ((const float4*)out)[i];
    int col = (int)((i * 4) & (D - 1));
    float4 w = *(const float4*)&lw[col];
    float4 b = *(const float4*)&lb[col];
    v.x = (v.x - mu) * rs * w.x + b.x;
    v.y = (v.y - mu) * rs * w.y + b.y;
    v.z = (v.z - mu) * rs * w.z + b.z;
    v.w = (v.w - mu) * rs * w.w + b.w;
    ((float4*)out)[i] = v;
}

extern "C" void kernel_launch(void* const* d_in, const int* in_sizes, int n_in,
                              void* d_out, int out_size, void* d_ws, size_t ws_size,
                              hipStream_t stream) {
    const float* x  = (const float*)d_in[0];
    const int*   ei = (const int*)d_in[1];
    const float* Wl = (const float*)d_in[2];
    const float* bl = (const float*)d_in[3];
    const float* Wr = (const float*)d_in[4];
    const float* lw = (const float*)d_in[5];
    const float* lb = (const float*)d_in[6];
    float* out = (float*)d_out;

    const int N = in_sizes[0] / D;       // 100000
    const int E = in_sizes[1] / 2;       // 1200000

    // ws layout (ints unless noted): stats(2 f32) | deg(N) | row_local(N) |
    //   partials(64) | row_ptr(N+1) | cursor(N) | adj(E)
    float* stats    = (float*)d_ws;
    int* deg        = (int*)d_ws + 2;
    int* row_local  = deg + N;
    int* partials   = row_local + N;
    int* row_ptr    = partials + 64;
    int* cursor     = row_ptr + (N + 1);
    int* adj        = cursor + N;

    // zero stats + deg only
    hipMemsetAsync(d_ws, 0, (size_t)(N + 2) * sizeof(int), stream);

    int be = (E + 255) / 256;
    hist_kernel<<<be, 256, 0, stream>>>(ei, deg, E, N);

    int nb = (N + SCAN_ELEMS - 1) / SCAN_ELEMS;       // 49 <= 64
    scan1_kernel<<<nb, 256, 0, stream>>>(deg, row_local, partials, N);
    scan2_kernel<<<1, 64, 0, stream>>>(partials, nb);
    scan3_kernel<<<(N + 256) / 256, 256, 0, stream>>>(row_local, partials,
                                                      row_ptr, cursor, N, E);

    fill_kernel<<<be, 256, 0, stream>>>(ei, cursor, adj, E, N);

    fused_kernel<<<1024, 256, 0, stream>>>(x, row_ptr, adj, Wl, bl, Wr,
                                           out, stats, N);

    long long M4 = (long long)N * D / 4;
    int blocks4 = (int)((M4 + 255) / 256);
    norm_kernel<<<blocks4, 256, 0, stream>>>(stats, lw, lb, out, M4);
}

// Round 3
// 438.784 us; speedup vs baseline: 1.0686x; 1.0686x over previous
//
#include <hip/hip_runtime.h>
#include <math.h>

#define EPS 1e-5f
constexpr int D = 64;
constexpr int SCAN_ELEMS = 2048;   // elements per scan1 block (256 thr * 8)

// ---------------- K1: degree histogram ----------------
__global__ void hist_kernel(const int* __restrict__ ei, int* __restrict__ deg,
                            int E, int N) {
    int e = blockIdx.x * blockDim.x + threadIdx.x;
    if (e >= E) return;
    int dst = ei[E + e];
    dst = min(max(dst, 0), N - 1);
    atomicAdd(&deg[dst], 1);
}

// ---------------- K2a: per-block exclusive scan ----------------
__global__ void scan1_kernel(const int* __restrict__ deg,
                             int* __restrict__ row_local,
                             int* __restrict__ partials, int N) {
    __shared__ int lds[256];
    int t = threadIdx.x;
    int base = blockIdx.x * SCAN_ELEMS;
    int v[8];
    int s = 0;
#pragma unroll
    for (int i = 0; i < 8; ++i) {
        int idx = base + t * 8 + i;
        int d = (idx < N) ? deg[idx] : 0;
        v[i] = s;           // exclusive within thread
        s += d;
    }
    lds[t] = s;
    __syncthreads();
    for (int off = 1; off < 256; off <<= 1) {
        int val = (t >= off) ? lds[t - off] : 0;
        __syncthreads();
        lds[t] += val;
        __syncthreads();
    }
    int thread_off = (t > 0) ? lds[t - 1] : 0;
    if (t == 255) partials[blockIdx.x] = lds[255];
#pragma unroll
    for (int i = 0; i < 8; ++i) {
        int idx = base + t * 8 + i;
        if (idx < N) row_local[idx] = thread_off + v[i];
    }
}

// ---------------- K2b: scan the block partials (nb <= 64) ----------------
__global__ void scan2_kernel(int* partials, int nb) {
    int t = threadIdx.x;
    int orig = (t < nb) ? partials[t] : 0;
    int v = orig;
    for (int off = 1; off < 64; off <<= 1) {
        int u = __shfl_up(v, off, 64);
        if (t >= off) v += u;
    }
    if (t < nb) partials[t] = v - orig;   // exclusive
}

// ---------------- K2c: add block offsets -> row_ptr, cursor ----------------
__global__ void scan3_kernel(const int* __restrict__ row_local,
                             const int* __restrict__ partials,
                             int* __restrict__ row_ptr, int* __restrict__ cursor,
                             int N, int E) {
    int i = blockIdx.x * blockDim.x + threadIdx.x;
    if (i < N) {
        int r = row_local[i] + partials[i / SCAN_ELEMS];
        row_ptr[i] = r;
        cursor[i] = r;
    } else if (i == N) {
        row_ptr[N] = E;
    }
}

// ---------------- K3: bucket fill (CSR adjacency) ----------------
__global__ void fill_kernel(const int* __restrict__ ei, int* __restrict__ cursor,
                            int* __restrict__ adj, int E, int N) {
    int e = blockIdx.x * blockDim.x + threadIdx.x;
    if (e >= E) return;
    int src = ei[e];
    int dst = ei[E + e];
    src = min(max(src, 0), N - 1);
    dst = min(max(dst, 0), N - 1);
    int pos = atomicAdd(&cursor[dst], 1);
    adj[pos] = src;
}

// ---- K4: gather + mean. Wave per node; lanes = 4 edge-slots x 16 col-quads.
// Writes mean row into `mean_out` (= d_out, consumed in-place by K5).
__global__ __launch_bounds__(256) void gather_kernel(
        const float* __restrict__ x, const int* __restrict__ row_ptr,
        const int* __restrict__ adj, float* __restrict__ mean_out, int N) {
    const int lane = threadIdx.x & 63;
    const int wid = blockIdx.x * (blockDim.x >> 6) + (threadIdx.x >> 6);
    const int nwaves = gridDim.x * (blockDim.x >> 6);
    const int sub = lane >> 4;           // edge slot 0..3
    const int c4 = (lane & 15) << 2;     // column base

    for (int n = wid; n < N; n += nwaves) {
        int r0 = row_ptr[n];
        int r1 = row_ptr[n + 1];
        float4 acc = make_float4(0.f, 0.f, 0.f, 0.f);
        for (int e = r0 + sub; e < r1; e += 4) {
            int src = adj[e];
            float4 v = *(const float4*)&x[(size_t)src * D + c4];
            acc.x += v.x; acc.y += v.y; acc.z += v.z; acc.w += v.w;
        }
        // reduce across the 4 edge-slots (lanes l, l^16, l^32, l^48)
        acc.x += __shfl_xor(acc.x, 16, 64);
        acc.y += __shfl_xor(acc.y, 16, 64);
        acc.z += __shfl_xor(acc.z, 16, 64);
        acc.w += __shfl_xor(acc.w, 16, 64);
        acc.x += __shfl_xor(acc.x, 32, 64);
        acc.y += __shfl_xor(acc.y, 32, 64);
        acc.z += __shfl_xor(acc.z, 32, 64);
        acc.w += __shfl_xor(acc.w, 32, 64);
        if (sub == 0) {
            float inv_c = 1.0f / fmaxf((float)(r1 - r0), 1.0f);
            float4 m;
            m.x = acc.x * inv_c; m.y = acc.y * inv_c;
            m.z = acc.z * inv_c; m.w = acc.w * inv_c;
            *(float4*)&mean_out[(size_t)n * D + c4] = m;
        }
    }
}

// ---- K5: out = mean @ Wl^T + b + x @ Wr^T (+ stats), in place on d_out ----
// Wave per node; lane j owns output col j, weights held in VGPRs.
__global__ __launch_bounds__(256, 2) void linear_kernel(
        const float* __restrict__ x, const float* __restrict__ Wl,
        const float* __restrict__ bl, const float* __restrict__ Wr,
        float* __restrict__ out, float* stats, int N) {
    const int lane = threadIdx.x & 63;
    const int wid = blockIdx.x * (blockDim.x >> 6) + (threadIdx.x >> 6);
    const int nwaves = gridDim.x * (blockDim.x >> 6);

    float wl[D], wr[D];
#pragma unroll
    for (int d4 = 0; d4 < D / 4; ++d4) {
        float4 a = *(const float4*)&Wl[lane * D + d4 * 4];
        float4 b = *(const float4*)&Wr[lane * D + d4 * 4];
        wl[d4 * 4 + 0] = a.x; wl[d4 * 4 + 1] = a.y;
        wl[d4 * 4 + 2] = a.z; wl[d4 * 4 + 3] = a.w;
        wr[d4 * 4 + 0] = b.x; wr[d4 * 4 + 1] = b.y;
        wr[d4 * 4 + 2] = b.z; wr[d4 * 4 + 3] = b.w;
    }
    const float bj = bl[lane];

    float ls = 0.0f, lsq = 0.0f;
    for (int n = wid; n < N; n += nwaves) {
        float sj = out[(size_t)n * D + lane];   // mean from gather_kernel
        float xj = x[(size_t)n * D + lane];
        float accl = 0.0f, accr = 0.0f;
#pragma unroll
        for (int d = 0; d < D; ++d) {
            float sd = __uint_as_float(
                __builtin_amdgcn_readlane(__float_as_uint(sj), d));
            float xd = __uint_as_float(
                __builtin_amdgcn_readlane(__float_as_uint(xj), d));
            accl = fmaf(sd, wl[d], accl);
            accr = fmaf(xd, wr[d], accr);
        }
        float v = accl + accr + bj;
        out[(size_t)n * D + lane] = v;
        ls += v;
        lsq += v * v;
    }
    for (int off = 32; off > 0; off >>= 1) {
        ls += __shfl_down(ls, off, 64);
        lsq += __shfl_down(lsq, off, 64);
    }
    if (lane == 0) {
        atomicAdd(&stats[0], ls);
        atomicAdd(&stats[1], lsq);
    }
}

// ---------------- K6: in-place graph layernorm on d_out ----------------
__global__ void norm_kernel(const float* __restrict__ stats,
                            const float* __restrict__ lw,
                            const float* __restrict__ lb,
                            float* out, long long M4) {
    long long i = (long long)blockIdx.x * blockDim.x + threadIdx.x;
    if (i >= M4) return;
    const float inv_M = 1.0f / (float)(M4 * 4);
    float mu = stats[0] * inv_M;
    float var = stats[1] * inv_M - mu * mu;
    float rs = 1.0f / sqrtf(var + EPS);
    float4 v = ((const float4*)out)[i];
    int col = (int)((i * 4) & (D - 1));
    float4 w = *(const float4*)&lw[col];
    float4 b = *(const float4*)&lb[col];
    v.x = (v.x - mu) * rs * w.x + b.x;
    v.y = (v.y - mu) * rs * w.y + b.y;
    v.z = (v.z - mu) * rs * w.z + b.z;
    v.w = (v.w - mu) * rs * w.w + b.w;
    ((float4*)out)[i] = v;
}

extern "C" void kernel_launch(void* const* d_in, const int* in_sizes, int n_in,
                              void* d_out, int out_size, void* d_ws, size_t ws_size,
                              hipStream_t stream) {
    const float* x  = (const float*)d_in[0];
    const int*   ei = (const int*)d_in[1];
    const float* Wl = (const float*)d_in[2];
    const float* bl = (const float*)d_in[3];
    const float* Wr = (const float*)d_in[4];
    const float* lw = (const float*)d_in[5];
    const float* lb = (const float*)d_in[6];
    float* out = (float*)d_out;

    const int N = in_sizes[0] / D;       // 100000
    const int E = in_sizes[1] / 2;       // 1200000

    // ws layout: stats(2 f32) | deg(N) | row_local(N) | partials(64) |
    //            row_ptr(N+1) | cursor(N) | adj(E)
    float* stats    = (float*)d_ws;
    int* deg        = (int*)d_ws + 2;
    int* row_local  = deg + N;
    int* partials   = row_local + N;
    int* row_ptr    = partials + 64;
    int* cursor     = row_ptr + (N + 1);
    int* adj        = cursor + N;

    hipMemsetAsync(d_ws, 0, (size_t)(N + 2) * sizeof(int), stream);

    int be = (E + 255) / 256;
    hist_kernel<<<be, 256, 0, stream>>>(ei, deg, E, N);

    int nb = (N + SCAN_ELEMS - 1) / SCAN_ELEMS;       // 49 <= 64
    scan1_kernel<<<nb, 256, 0, stream>>>(deg, row_local, partials, N);
    scan2_kernel<<<1, 64, 0, stream>>>(partials, nb);
    scan3_kernel<<<(N + 256) / 256, 256, 0, stream>>>(row_local, partials,
                                                      row_ptr, cursor, N, E);

    fill_kernel<<<be, 256, 0, stream>>>(ei, cursor, adj, E, N);

    gather_kernel<<<2048, 256, 0, stream>>>(x, row_ptr, adj, out, N);

    linear_kernel<<<2048, 256, 0, stream>>>(x, Wl, bl, Wr, out, stats, N);

    long long M4 = (long long)N * D / 4;
    int blocks4 = (int)((M4 + 255) / 256);
    norm_kernel<<<blocks4, 256, 0, stream>>>(stats, lw, lb, out, M4);
}

// Round 4
// 276.505 us; speedup vs baseline: 1.6958x; 1.5869x over previous
//
#include <hip/hip_runtime.h>
#include <math.h>

#define EPS 1e-5f
constexpr int D = 64;
constexpr int SCAN_ELEMS = 2048;

typedef __attribute__((ext_vector_type(8))) short bf16x8;
typedef __attribute__((ext_vector_type(4))) float f32x4;

__device__ __forceinline__ ushort f32_to_bf16_rne(float v) {
    unsigned u = __float_as_uint(v);
    return (ushort)((u + 0x7FFFu + ((u >> 16) & 1u)) >> 16);
}

// ---------------- K1: degree histogram ----------------
__global__ void hist_kernel(const int* __restrict__ ei, int* __restrict__ deg,
                            int E, int N) {
    int e = blockIdx.x * blockDim.x + threadIdx.x;
    if (e >= E) return;
    int dst = ei[E + e];
    dst = min(max(dst, 0), N - 1);
    atomicAdd(&deg[dst], 1);
}

// ---------------- K2a: per-block exclusive scan ----------------
__global__ void scan1_kernel(const int* __restrict__ deg,
                             int* __restrict__ row_local,
                             int* __restrict__ partials, int N) {
    __shared__ int lds[256];
    int t = threadIdx.x;
    int base = blockIdx.x * SCAN_ELEMS;
    int v[8];
    int s = 0;
#pragma unroll
    for (int i = 0; i < 8; ++i) {
        int idx = base + t * 8 + i;
        int d = (idx < N) ? deg[idx] : 0;
        v[i] = s;
        s += d;
    }
    lds[t] = s;
    __syncthreads();
    for (int off = 1; off < 256; off <<= 1) {
        int val = (t >= off) ? lds[t - off] : 0;
        __syncthreads();
        lds[t] += val;
        __syncthreads();
    }
    int thread_off = (t > 0) ? lds[t - 1] : 0;
    if (t == 255) partials[blockIdx.x] = lds[255];
#pragma unroll
    for (int i = 0; i < 8; ++i) {
        int idx = base + t * 8 + i;
        if (idx < N) row_local[idx] = thread_off + v[i];
    }
}

// ---------------- K2b: scan the block partials (nb <= 64) ----------------
__global__ void scan2_kernel(int* partials, int nb) {
    int t = threadIdx.x;
    int orig = (t < nb) ? partials[t] : 0;
    int v = orig;
    for (int off = 1; off < 64; off <<= 1) {
        int u = __shfl_up(v, off, 64);
        if (t >= off) v += u;
    }
    if (t < nb) partials[t] = v - orig;
}

// ---------------- K2c: add block offsets -> row_ptr, cursor ----------------
__global__ void scan3_kernel(const int* __restrict__ row_local,
                             const int* __restrict__ partials,
                             int* __restrict__ row_ptr, int* __restrict__ cursor,
                             int N, int E) {
    int i = blockIdx.x * blockDim.x + threadIdx.x;
    if (i < N) {
        int r = row_local[i] + partials[i / SCAN_ELEMS];
        row_ptr[i] = r;
        cursor[i] = r;
    } else if (i == N) {
        row_ptr[N] = E;
    }
}

// ---------------- K3: bucket fill (CSR adjacency) ----------------
__global__ void fill_kernel(const int* __restrict__ ei, int* __restrict__ cursor,
                            int* __restrict__ adj, int E, int N) {
    int e = blockIdx.x * blockDim.x + threadIdx.x;
    if (e >= E) return;
    int src = ei[e];
    int dst = ei[E + e];
    src = min(max(src, 0), N - 1);
    dst = min(max(dst, 0), N - 1);
    int pos = atomicAdd(&cursor[dst], 1);
    adj[pos] = src;
}

// ---- K4: gather + mean. Wave per node; lanes = 4 edge-slots x 16 col-quads.
__global__ __launch_bounds__(256) void gather_kernel(
        const float* __restrict__ x, const int* __restrict__ row_ptr,
        const int* __restrict__ adj, float* __restrict__ mean_out, int N) {
    const int lane = threadIdx.x & 63;
    const int wid = blockIdx.x * (blockDim.x >> 6) + (threadIdx.x >> 6);
    const int nwaves = gridDim.x * (blockDim.x >> 6);
    const int sub = lane >> 4;
    const int c4 = (lane & 15) << 2;

    for (int n = wid; n < N; n += nwaves) {
        int r0 = row_ptr[n];
        int r1 = row_ptr[n + 1];
        float4 acc = make_float4(0.f, 0.f, 0.f, 0.f);
        for (int e = r0 + sub; e < r1; e += 4) {
            int src = adj[e];
            float4 v = *(const float4*)&x[(size_t)src * D + c4];
            acc.x += v.x; acc.y += v.y; acc.z += v.z; acc.w += v.w;
        }
        acc.x += __shfl_xor(acc.x, 16, 64);
        acc.y += __shfl_xor(acc.y, 16, 64);
        acc.z += __shfl_xor(acc.z, 16, 64);
        acc.w += __shfl_xor(acc.w, 16, 64);
        acc.x += __shfl_xor(acc.x, 32, 64);
        acc.y += __shfl_xor(acc.y, 32, 64);
        acc.z += __shfl_xor(acc.z, 32, 64);
        acc.w += __shfl_xor(acc.w, 32, 64);
        if (sub == 0) {
            float inv_c = 1.0f / fmaxf((float)(r1 - r0), 1.0f);
            float4 m;
            m.x = acc.x * inv_c; m.y = acc.y * inv_c;
            m.z = acc.z * inv_c; m.w = acc.w * inv_c;
            *(float4*)&mean_out[(size_t)n * D + c4] = m;
        }
    }
}

// ---- K4b: pack Wl/Wr into MFMA B-fragment order, bf16 hi/lo ----
// frag id = mat*16 + hl*8 + ct*2 + kh ; packed[(frag*64+lane)*8 + j]
// B[k][col] = W[col][k]; lane holds col=(lane&15)+16*ct, k=(lane>>4)*8+32*kh+j
__global__ void pack_w_kernel(const float* __restrict__ Wl,
                              const float* __restrict__ Wr,
                              ushort* __restrict__ packed) {
    int t = blockIdx.x * blockDim.x + threadIdx.x;
    if (t >= 2048) return;
    int lane = t & 63;
    int frag = t >> 6;
    int kh = frag & 1;
    int ct = (frag >> 1) & 3;
    int hl = (frag >> 3) & 1;
    int mat = (frag >> 4) & 1;
    const float* W = mat ? Wr : Wl;
    int j = (lane & 15) + 16 * ct;
    int d0 = (lane >> 4) * 8 + 32 * kh;
    ushort o[8];
#pragma unroll
    for (int i = 0; i < 8; ++i) {
        float v = W[j * 64 + d0 + i];
        ushort hi = f32_to_bf16_rne(v);
        if (hl == 0) {
            o[i] = hi;
        } else {
            float r = v - __uint_as_float(((unsigned)hi) << 16);
            o[i] = f32_to_bf16_rne(r);
        }
    }
    bf16x8 w;
#pragma unroll
    for (int i = 0; i < 8; ++i) w[i] = (short)o[i];
    *(bf16x8*)&packed[(size_t)t * 8] = w;
}

// ---- K5: MFMA linear: out = mean @ Wl^T + b + x @ Wr^T (+ stats) ----
// Wave per 16-row group. B-frags (32 x bf16x8 = 128 VGPR) loaded once.
__global__ __launch_bounds__(256, 2) void linear_mfma_kernel(
        const float* __restrict__ x, const ushort* __restrict__ packed,
        const float* __restrict__ bl, float* out, float* stats, int G, int N) {
    const int lane = threadIdx.x & 63;
    const int wid = blockIdx.x * (blockDim.x >> 6) + (threadIdx.x >> 6);
    const int nwaves = gridDim.x * (blockDim.x >> 6);
    const int r16 = lane & 15;
    const int kblk = lane >> 4;

    bf16x8 bfrag[2][2][4][2];   // [mat][hl][ct][kh]
#pragma unroll
    for (int mat = 0; mat < 2; ++mat)
#pragma unroll
        for (int hl = 0; hl < 2; ++hl)
#pragma unroll
            for (int ct = 0; ct < 4; ++ct)
#pragma unroll
                for (int kh = 0; kh < 2; ++kh) {
                    int frag = mat * 16 + hl * 8 + ct * 2 + kh;
                    bfrag[mat][hl][ct][kh] =
                        *(const bf16x8*)&packed[((size_t)frag * 64 + lane) * 8];
                }
    float blv[4];
#pragma unroll
    for (int ct = 0; ct < 4; ++ct) blv[ct] = bl[16 * ct + r16];

    float ls = 0.0f, lsq = 0.0f;
    for (int g = wid; g < G; g += nwaves) {
        int rowbase = g * 16;
        int arow = min(rowbase + r16, N - 1);
        bf16x8 ahi[2][2], alo[2][2];   // [mat][kh]
#pragma unroll
        for (int mat = 0; mat < 2; ++mat) {
            const float* src = mat ? x : out;
#pragma unroll
            for (int kh = 0; kh < 2; ++kh) {
                const float* p = &src[(size_t)arow * D + kblk * 8 + kh * 32];
                float4 v0 = *(const float4*)p;
                float4 v1 = *(const float4*)(p + 4);
                float vv[8] = {v0.x, v0.y, v0.z, v0.w, v1.x, v1.y, v1.z, v1.w};
                bf16x8 h, l;
#pragma unroll
                for (int i = 0; i < 8; ++i) {
                    ushort hu = f32_to_bf16_rne(vv[i]);
                    h[i] = (short)hu;
                    float r = vv[i] - __uint_as_float(((unsigned)hu) << 16);
                    l[i] = (short)f32_to_bf16_rne(r);
                }
                ahi[mat][kh] = h;
                alo[mat][kh] = l;
            }
        }
        f32x4 acc[4];
#pragma unroll
        for (int ct = 0; ct < 4; ++ct) acc[ct] = (f32x4)(0.0f);
#pragma unroll
        for (int ct = 0; ct < 4; ++ct)
#pragma unroll
            for (int mat = 0; mat < 2; ++mat)
#pragma unroll
                for (int kh = 0; kh < 2; ++kh) {
                    acc[ct] = __builtin_amdgcn_mfma_f32_16x16x32_bf16(
                        ahi[mat][kh], bfrag[mat][0][ct][kh], acc[ct], 0, 0, 0);
                    acc[ct] = __builtin_amdgcn_mfma_f32_16x16x32_bf16(
                        ahi[mat][kh], bfrag[mat][1][ct][kh], acc[ct], 0, 0, 0);
                    acc[ct] = __builtin_amdgcn_mfma_f32_16x16x32_bf16(
                        alo[mat][kh], bfrag[mat][0][ct][kh], acc[ct], 0, 0, 0);
                }
        // epilogue: row = rowbase + kblk*4 + r, col = 16*ct + r16
#pragma unroll
        for (int ct = 0; ct < 4; ++ct) {
#pragma unroll
            for (int r = 0; r < 4; ++r) {
                int row = rowbase + kblk * 4 + r;
                if (row < N) {
                    float v = acc[ct][r] + blv[ct];
                    out[(size_t)row * D + 16 * ct + r16] = v;
                    ls += v;
                    lsq += v * v;
                }
            }
        }
    }
    for (int off = 32; off > 0; off >>= 1) {
        ls += __shfl_down(ls, off, 64);
        lsq += __shfl_down(lsq, off, 64);
    }
    if (lane == 0) {
        atomicAdd(&stats[0], ls);
        atomicAdd(&stats[1], lsq);
    }
}

// ---------------- K6: in-place graph layernorm on d_out ----------------
__global__ void norm_kernel(const float* __restrict__ stats,
                            const float* __restrict__ lw,
                            const float* __restrict__ lb,
                            float* out, long long M4) {
    long long i = (long long)blockIdx.x * blockDim.x + threadIdx.x;
    if (i >= M4) return;
    const float inv_M = 1.0f / (float)(M4 * 4);
    float mu = stats[0] * inv_M;
    float var = stats[1] * inv_M - mu * mu;
    float rs = 1.0f / sqrtf(var + EPS);
    float4 v = ((const float4*)out)[i];
    int col = (int)((i * 4) & (D - 1));
    float4 w = *(const float4*)&lw[col];
    float4 b = *(const float4*)&lb[col];
    v.x = (v.x - mu) * rs * w.x + b.x;
    v.y = (v.y - mu) * rs * w.y + b.y;
    v.z = (v.z - mu) * rs * w.z + b.z;
    v.w = (v.w - mu) * rs * w.w + b.w;
    ((float4*)out)[i] = v;
}

extern "C" void kernel_launch(void* const* d_in, const int* in_sizes, int n_in,
                              void* d_out, int out_size, void* d_ws, size_t ws_size,
                              hipStream_t stream) {
    const float* x  = (const float*)d_in[0];
    const int*   ei = (const int*)d_in[1];
    const float* Wl = (const float*)d_in[2];
    const float* bl = (const float*)d_in[3];
    const float* Wr = (const float*)d_in[4];
    const float* lw = (const float*)d_in[5];
    const float* lb = (const float*)d_in[6];
    float* out = (float*)d_out;

    const int N = in_sizes[0] / D;       // 100000
    const int E = in_sizes[1] / 2;       // 1200000

    // ws layout: stats(2 f32) | deg(N) | row_local(N) | partials(64) |
    //            row_ptr(N+1) | cursor(N) | adj(E) | packed_w(2048*8 ushort)
    float* stats    = (float*)d_ws;
    int* deg        = (int*)d_ws + 2;
    int* row_local  = deg + N;
    int* partials   = row_local + N;
    int* row_ptr    = partials + 64;
    int* cursor     = row_ptr + (N + 1);
    int* adj        = cursor + N;
    ushort* packedw = (ushort*)(adj + E);

    hipMemsetAsync(d_ws, 0, (size_t)(N + 2) * sizeof(int), stream);

    pack_w_kernel<<<8, 256, 0, stream>>>(Wl, Wr, packedw);

    int be = (E + 255) / 256;
    hist_kernel<<<be, 256, 0, stream>>>(ei, deg, E, N);

    int nb = (N + SCAN_ELEMS - 1) / SCAN_ELEMS;
    scan1_kernel<<<nb, 256, 0, stream>>>(deg, row_local, partials, N);
    scan2_kernel<<<1, 64, 0, stream>>>(partials, nb);
    scan3_kernel<<<(N + 256) / 256, 256, 0, stream>>>(row_local, partials,
                                                      row_ptr, cursor, N, E);

    fill_kernel<<<be, 256, 0, stream>>>(ei, cursor, adj, E, N);

    gather_kernel<<<2048, 256, 0, stream>>>(x, row_ptr, adj, out, N);

    int G = (N + 15) / 16;   // 6250
    linear_mfma_kernel<<<512, 256, 0, stream>>>(x, packedw, bl, out, stats, G, N);

    long long M4 = (long long)N * D / 4;
    int blocks4 = (int)((M4 + 255) / 256);
    norm_kernel<<<blocks4, 256, 0, stream>>>(stats, lw, lb, out, M4);
}